// Round 2
// baseline (184.660 us; speedup 1.0000x reference)
//
#include <hip/hip_runtime.h>
#include <stdint.h>

typedef unsigned int u32;
typedef unsigned short u16;
typedef u32 u32x4 __attribute__((ext_vector_type(4)));
typedef float f32x4 __attribute__((ext_vector_type(4)));

#define MEM_DIM 256
#define FEA 1000
#define FPAD 1024
#define BM 128          // rows per block (4 waves x 32 rows)
#define NIT 32          // f-iterations of BF=32
#define NOUT 33554432   // 32*64*64*256

// f32 -> bf16 (RNE, valid for finite normals/zero) in pure integer ops
__device__ __forceinline__ u16 f2bf(float x) {
  u32 u = __builtin_bit_cast(u32, x);
  u32 r = (u + 0x7fffu + ((u >> 16) & 1u)) >> 16;
  return (u16)r;
}

// pack two f32 -> one u32 of 2 bf16 (RNE), low half = first element
__device__ __forceinline__ u32 packbf(float a, float b) {
  return (u32)f2bf(a) | ((u32)f2bf(b) << 16);
}

// D = A*B + D, A/B = 8 bf16 per lane (4 VGPR). Inline asm: type-agnostic operands.
__device__ __forceinline__ void mfma16(f32x4& acc, u32x4 a, u32x4 b) {
  asm("v_mfma_f32_16x16x32_bf16 %0, %1, %2, %0" : "+v"(acc) : "v"(a), "v"(b));
}

#define GLOAD_LDS16(gp, lp) __builtin_amdgcn_global_load_lds( \
    (const __attribute__((address_space(1))) u32*)(gp),       \
    (__attribute__((address_space(3))) u32*)(lp), 16, 0, 0)

// Build swizzled bf16 W and W^T in workspace. Swizzle is baked into global
// layout so linear global_load_lds staging produces conflict-free LDS.
// Wswz[f][c ^ ((f&7)<<3)]  (row-major, 1024x256, rows>=1000 zero)
// Wt  [c][f ^ ((c&3)<<3)]  (transposed,  256x1024, cols>=1000 zero)
__global__ void prep_kernel(const float* __restrict__ W, u16* __restrict__ Wswz,
                            u16* __restrict__ Wt, float* __restrict__ entpart) {
  int f = blockIdx.x;   // 0..1023
  int c = threadIdx.x;  // 0..255
  float v = (f < FEA) ? W[f * MEM_DIM + c] : 0.0f;
  u16 b = f2bf(v);
  Wswz[f * MEM_DIM + (c ^ ((f & 7) << 3))] = b;
  Wt[c * FPAD + (f ^ ((c & 3) << 3))] = b;
  if (blockIdx.x < 4) entpart[blockIdx.x * 256 + threadIdx.x] = 0.0f;
}

// Fused: S = X*W^T (swapped: St[f][m] = mfma(W,X)), p = e^s (no max needed,
// |s|<~5), accumulate Z=sum p, T=sum p*s, O_raw += P*W; out = O_raw/Z,
// ent_row = ln Z - T/Z.
__global__ __launch_bounds__(256, 2) void fused_kernel(
    const float* __restrict__ X, const u16* __restrict__ Wswz,
    const u16* __restrict__ Wt, float* __restrict__ Out,
    float* __restrict__ entpart) {
  // LDS: Wb dbuf [2][32][256]bf16 @0 (2x16KB), Wt dbuf [2][256][32]bf16 @32768
  __shared__ __attribute__((aligned(16))) char smem[65536];
  __shared__ float entw[4];
  const int tid = threadIdx.x;
  const int wave = tid >> 6;
  const int lane = tid & 63;
  const int g = lane >> 4;   // 0..3
  const int q = lane & 15;   // 0..15
  const long rowbase = (long)blockIdx.x * BM + wave * 32;

  // ---- X fragments in registers: B-operand, lane holds X[m=q][k=8g+e] ----
  u32x4 xf[2][8];  // [msub][kk]
#pragma unroll
  for (int ms = 0; ms < 2; ++ms) {
    const float* xr = X + (rowbase + ms * 16 + q) * MEM_DIM;
#pragma unroll
    for (int kk = 0; kk < 8; ++kk) {
      const f32x4* p = (const f32x4*)(xr + kk * 32 + g * 8);
      f32x4 a = p[0], b = p[1];
      u32x4 v;
      v.x = packbf(a.x, a.y); v.y = packbf(a.z, a.w);
      v.z = packbf(b.x, b.y); v.w = packbf(b.z, b.w);
      xf[ms][kk] = v;
    }
  }

  const char* WswzB = (const char*)Wswz;
  const char* WtB = (const char*)Wt;
  auto stage = [&](int it, int buf) {
    // Wb chunk: rows [32it,32it+32) contiguous 16KB; 16 instrs, 4/wave
#pragma unroll
    for (int jj = 0; jj < 4; ++jj) {
      int j = wave * 4 + jj;
      GLOAD_LDS16(WswzB + (size_t)it * 16384 + j * 1024 + lane * 16,
                  smem + buf * 16384 + j * 1024);
    }
    // Wt chunk: [256 c][32 f] = 64B per row, strided
#pragma unroll
    for (int jj = 0; jj < 4; ++jj) {
      int j = wave * 4 + jj;
      GLOAD_LDS16(WtB + (size_t)it * 64 + (size_t)(16 * j + (lane >> 2)) * 2048
                      + (lane & 3) * 16,
                  smem + 32768 + buf * 16384 + j * 1024);
    }
  };

  f32x4 ot[16][2];  // O^T accum: [ctile][msub], lane holds Ot[c=16ct+4g+r][m=16ms+q]
  f32x4 z4 = {0.f, 0.f, 0.f, 0.f};
#pragma unroll
  for (int i = 0; i < 16; ++i) { ot[i][0] = z4; ot[i][1] = z4; }
  float zz[2] = {0.f, 0.f}, tt[2] = {0.f, 0.f};

  stage(0, 0);
  asm volatile("s_waitcnt vmcnt(0)" ::: "memory");
  __syncthreads();

  for (int it = 0; it < NIT; ++it) {
    const int cur = it & 1;
    if (it + 1 < NIT) stage(it + 1, cur ^ 1);
    const char* wb = smem + cur * 16384;
    const char* wt = smem + 32768 + cur * 16384;

    // GEMM1': St[f][m], A=W rows (i=16fs+q, k=32kk+8g+e), B=X
    f32x4 st[2][2];
    st[0][0] = z4; st[0][1] = z4; st[1][0] = z4; st[1][1] = z4;
#pragma unroll
    for (int kk = 0; kk < 8; ++kk) {
#pragma unroll
      for (int fs = 0; fs < 2; ++fs) {
        const int fl = fs * 16 + q;
        const int off = fl * 512 + ((kk * 64 + g * 16) ^ ((fl & 7) << 4));
        u32x4 wfrag = *(const u32x4*)(wb + off);
        mfma16(st[fs][0], wfrag, xf[0][kk]);
        mfma16(st[fs][1], wfrag, xf[1][kk]);
      }
    }

    // softmax partials; lane holds St[f=32it+16fs+4g+r][m=16ms+q]
    const int fbase = it * 32;
    u32 pw[2][2][2];  // packed bf16 pairs: [fs][ms][rows(4g,4g+1)|(4g+2,4g+3)]
#pragma unroll
    for (int fs = 0; fs < 2; ++fs) {
#pragma unroll
      for (int ms = 0; ms < 2; ++ms) {
        float pv[4];
#pragma unroll
        for (int r = 0; r < 4; ++r) {
          float s = st[fs][ms][r];
          int fg = fbase + fs * 16 + g * 4 + r;
          float p = (fg < FEA) ? __expf(s) : 0.0f;
          pv[r] = p;
          zz[ms] += p;
          tt[ms] += p * s;
        }
        pw[fs][ms][0] = packbf(pv[0], pv[1]);
        pw[fs][ms][1] = packbf(pv[2], pv[3]);
      }
    }

    // redistribute P (C-layout) -> B-frag: lane needs P[f=8g+2w+h][m=q]
    u32x4 pfrag[2];
#pragma unroll
    for (int ms = 0; ms < 2; ++ms) {
      u32 wd[4];
#pragma unroll
      for (int w = 0; w < 4; ++w) {
        int src = ((2 * (g & 1) + (w >> 1)) << 4) | q;
        u32 v0 = (u32)__shfl((int)pw[0][ms][w & 1], src, 64);
        u32 v1 = (u32)__shfl((int)pw[1][ms][w & 1], src, 64);
        wd[w] = (g >= 2) ? v1 : v0;
      }
      u32x4 pf; pf.x = wd[0]; pf.y = wd[1]; pf.z = wd[2]; pf.w = wd[3];
      pfrag[ms] = pf;
    }

    // GEMM2': Ot[c][m] += Wt-frag (i=16ct+q, k=f) * P-frag
#pragma unroll
    for (int ct = 0; ct < 16; ++ct) {
      const int c = ct * 16 + q;
      const int off = c * 64 + ((g << 4) ^ ((c & 3) << 4));
      u32x4 wtfrag = *(const u32x4*)(wt + off);
      mfma16(ot[ct][0], wtfrag, pfrag[0]);
      mfma16(ot[ct][1], wtfrag, pfrag[1]);
    }

    asm volatile("s_waitcnt vmcnt(0)" ::: "memory");
    __syncthreads();
  }

  // Z/T full per-row sums: reduce over 4 g-replica lanes (xor 16,32)
#pragma unroll
  for (int ms = 0; ms < 2; ++ms) {
    zz[ms] += __shfl_xor(zz[ms], 16, 64);
    zz[ms] += __shfl_xor(zz[ms], 32, 64);
    tt[ms] += __shfl_xor(tt[ms], 16, 64);
    tt[ms] += __shfl_xor(tt[ms], 32, 64);
  }

  // entropy partial: sum of (ln Z - T/Z) over wave's 32 rows (4x replicated)
  float er = 0.0f;
#pragma unroll
  for (int ms = 0; ms < 2; ++ms) er += __logf(zz[ms]) - tt[ms] / zz[ms];
#pragma unroll
  for (int d = 1; d < 64; d <<= 1) er += __shfl_xor(er, d, 64);
  if (lane == 0) entw[wave] = er * 0.25f;

  // normalize + store O (float4, coalesced: 16 rows x 64B per instr)
#pragma unroll
  for (int ms = 0; ms < 2; ++ms) {
    float rz = 1.0f / zz[ms];
    float* orow = Out + (rowbase + ms * 16 + q) * MEM_DIM;
#pragma unroll
    for (int ct = 0; ct < 16; ++ct) {
      f32x4 v = ot[ct][ms] * rz;
      *(f32x4*)(orow + ct * 16 + g * 4) = v;
    }
  }

  __syncthreads();
  if (tid == 0) entpart[blockIdx.x] = entw[0] + entw[1] + entw[2] + entw[3];
}

// batch b = 32 consecutive block partials; mean over H*W*F = 4096*1000
__global__ void ent_final(const float* __restrict__ entpart,
                          float* __restrict__ entout) {
  int b = blockIdx.x;
  int l = threadIdx.x;
  float v = (l < 32) ? entpart[b * 32 + l] : 0.0f;
#pragma unroll
  for (int d = 1; d < 64; d <<= 1) v += __shfl_xor(v, d, 64);
  if (l == 0) entout[b] = v * (1.0f / 4096000.0f);
}

extern "C" void kernel_launch(void* const* d_in, const int* in_sizes, int n_in,
                              void* d_out, int out_size, void* d_ws, size_t ws_size,
                              hipStream_t stream) {
  (void)in_sizes; (void)n_in; (void)out_size;
  const float* X = (const float*)d_in[0];   // [131072, 256] f32
  const float* W = (const float*)d_in[1];   // [1000, 256] f32
  float* Out = (float*)d_out;               // [131072,256] f32 then [32] ent
  u16* Wswz = (u16*)d_ws;                           // 512 KB
  u16* Wt = (u16*)((char*)d_ws + 524288);           // 512 KB
  float* entpart = (float*)((char*)d_ws + 1048576); // 4 KB
  if (ws_size < 1048576 + 4096) return;  // workspace too small (not expected)
  prep_kernel<<<dim3(1024), dim3(256), 0, stream>>>(W, Wswz, Wt, entpart);
  fused_kernel<<<dim3(1024), dim3(256), 0, stream>>>(X, Wswz, Wt, Out, entpart);
  ent_final<<<dim3(32), dim3(64), 0, stream>>>(entpart, Out + NOUT);
}

// Round 4
// 182.018 us; speedup vs baseline: 1.0145x; 1.0145x over previous
//
#include <hip/hip_runtime.h>
#include <stdint.h>

typedef unsigned int u32;
typedef unsigned short u16;
typedef u32 u32x4 __attribute__((ext_vector_type(4)));
typedef float f32x4 __attribute__((ext_vector_type(4)));

#define MEM_DIM 256
#define FEA 1000
#define FPAD 1024
#define BM 128          // rows per block (4 waves x 32 rows)
#define NIT 32          // f-iterations of BF=32
#define NOUT 33554432   // 32*64*64*256

// f32 -> bf16 (RNE, valid for finite normals/zero) in pure integer ops
__device__ __forceinline__ u16 f2bf(float x) {
  u32 u = __builtin_bit_cast(u32, x);
  u32 r = (u + 0x7fffu + ((u >> 16) & 1u)) >> 16;
  return (u16)r;
}

__device__ __forceinline__ u32 packbf(float a, float b) {
  return (u32)f2bf(a) | ((u32)f2bf(b) << 16);
}

__device__ __forceinline__ void mfma16(f32x4& acc, u32x4 a, u32x4 b) {
  asm("v_mfma_f32_16x16x32_bf16 %0, %1, %2, %0" : "+v"(acc) : "v"(a), "v"(b));
}

#define GLOAD_LDS16(gp, lp) __builtin_amdgcn_global_load_lds( \
    (const __attribute__((address_space(1))) u32*)(gp),       \
    (__attribute__((address_space(3))) u32*)(lp), 16, 0, 0)

// Build swizzled bf16 W and W^T in workspace (R2 layouts, except Wt swizzle).
// Wswz[f][c ^ ((f&7)<<3)]  (row-major, 1024x256, rows>=1000 zero) -- natural f
// Wt  [c][f ^ (((c>>1)&3)<<3)]  (transposed, 256x1024, cols>=1000 zero)
//   ((c>>1)&3) instead of (c&3): quarter-wave lanes then hit 8 distinct
//   start-banks x 2-way (free, m136) instead of 4-way on ds_read_b128.
__global__ void prep_kernel(const float* __restrict__ W, u16* __restrict__ Wswz,
                            u16* __restrict__ Wt, float* __restrict__ entpart) {
  int f = blockIdx.x;   // 0..1023
  int c = threadIdx.x;  // 0..255
  float v = (f < FEA) ? W[f * MEM_DIM + c] : 0.0f;
  u16 b = f2bf(v);
  Wswz[f * MEM_DIM + (c ^ ((f & 7) << 3))] = b;
  Wt[c * FPAD + (f ^ (((c >> 1) & 3) << 3))] = b;
  if (blockIdx.x < 4) entpart[blockIdx.x * 256 + threadIdx.x] = 0.0f;
}

// Fused: S = X*W^T (swapped: St[f][m] = mfma(W,X)), p = e^s (no max needed,
// |s|<~5), accumulate Z=sum p, T=sum p*s, O_raw += P*W; out = O_raw/Z,
// ent_row = ln Z - T/Z.  (Exact R2 structure: natural-f rows, shfl
// redistribution, fg<FEA pad mask -- bit-identical math to the passing R2.)
__global__ __launch_bounds__(256, 2) void fused_kernel(
    const float* __restrict__ X, const u16* __restrict__ Wswz,
    const u16* __restrict__ Wt, float* __restrict__ Out,
    float* __restrict__ entpart) {
  // LDS: Wb dbuf [2][32][256]bf16 @0 (2x16KB), Wt dbuf [2][256][32]bf16 @32768
  __shared__ __attribute__((aligned(16))) char smem[65536];
  __shared__ float entw[4];
  const int tid = threadIdx.x;
  const int wave = tid >> 6;
  const int lane = tid & 63;
  const int g = lane >> 4;   // 0..3
  const int q = lane & 15;   // 0..15
  const long rowbase = (long)blockIdx.x * BM + wave * 32;

  // X fragments: B-operand, lane holds X[m=q][k=8g+e]
  u32x4 xf[2][8];  // [msub][kk]
#pragma unroll
  for (int ms = 0; ms < 2; ++ms) {
    const float* xr = X + (rowbase + ms * 16 + q) * MEM_DIM;
#pragma unroll
    for (int kk = 0; kk < 8; ++kk) {
      const f32x4* p = (const f32x4*)(xr + kk * 32 + g * 8);
      f32x4 a = p[0], b = p[1];
      u32x4 v;
      v.x = packbf(a.x, a.y); v.y = packbf(a.z, a.w);
      v.z = packbf(b.x, b.y); v.w = packbf(b.z, b.w);
      xf[ms][kk] = v;
    }
  }

  const char* WswzB = (const char*)Wswz;
  const char* WtB = (const char*)Wt;
  auto stage = [&](int it, int buf) {
#pragma unroll
    for (int jj = 0; jj < 4; ++jj) {
      int j = wave * 4 + jj;
      GLOAD_LDS16(WswzB + (size_t)it * 16384 + j * 1024 + lane * 16,
                  smem + buf * 16384 + j * 1024);
    }
#pragma unroll
    for (int jj = 0; jj < 4; ++jj) {
      int j = wave * 4 + jj;
      GLOAD_LDS16(WtB + (size_t)it * 64 + (size_t)(16 * j + (lane >> 2)) * 2048
                      + (lane & 3) * 16,
                  smem + 32768 + buf * 16384 + j * 1024);
    }
  };

  f32x4 ot[16][2];  // [ctile][msub]: lane holds Ot[c=16ct+4g+r][m=16ms+q]
  f32x4 z4 = {0.f, 0.f, 0.f, 0.f};
#pragma unroll
  for (int i = 0; i < 16; ++i) { ot[i][0] = z4; ot[i][1] = z4; }
  float zz[2] = {0.f, 0.f}, tt[2] = {0.f, 0.f};

  stage(0, 0);
  asm volatile("s_waitcnt vmcnt(0)" ::: "memory");
  __syncthreads();

  for (int it = 0; it < NIT; ++it) {
    const int cur = it & 1;
    if (it + 1 < NIT) stage(it + 1, cur ^ 1);
    const char* wb = smem + cur * 16384;
    const char* wt = smem + 32768 + cur * 16384;

    // GEMM1': St[f][m], A=W rows (i=16fs+q, k=32kk+8g+e), B=X
    f32x4 st[2][2];
    st[0][0] = z4; st[0][1] = z4; st[1][0] = z4; st[1][1] = z4;
#pragma unroll
    for (int kk = 0; kk < 8; ++kk) {
#pragma unroll
      for (int fs = 0; fs < 2; ++fs) {
        const int fl = fs * 16 + q;
        const int off = fl * 512 + ((kk * 64 + g * 16) ^ ((fl & 7) << 4));
        u32x4 wfrag = *(const u32x4*)(wb + off);
        mfma16(st[fs][0], wfrag, xf[0][kk]);
        mfma16(st[fs][1], wfrag, xf[1][kk]);
      }
    }

    // softmax partials; lane holds St[f=32it+16fs+4g+r][m=16ms+q]
    const int fbase = it * 32;
    u32 pw[2][2][2];  // packed bf16 pairs: [fs][ms][rows(4g,4g+1)|(4g+2,4g+3)]
#pragma unroll
    for (int fs = 0; fs < 2; ++fs) {
#pragma unroll
      for (int ms = 0; ms < 2; ++ms) {
        float pv[4];
#pragma unroll
        for (int r = 0; r < 4; ++r) {
          float s = st[fs][ms][r];
          int fg = fbase + fs * 16 + g * 4 + r;
          float p = (fg < FEA) ? __expf(s) : 0.0f;
          pv[r] = p;
          zz[ms] += p;
          tt[ms] += p * s;
        }
        pw[fs][ms][0] = packbf(pv[0], pv[1]);
        pw[fs][ms][1] = packbf(pv[2], pv[3]);
      }
    }

    // redistribute P (C-layout) -> B-frag: lane needs P[f=8g+2w+h][m=q]
    u32x4 pfrag[2];
#pragma unroll
    for (int ms = 0; ms < 2; ++ms) {
      u32 wd[4];
#pragma unroll
      for (int w = 0; w < 4; ++w) {
        int src = ((2 * (g & 1) + (w >> 1)) << 4) | q;
        u32 v0 = (u32)__shfl((int)pw[0][ms][w & 1], src, 64);
        u32 v1 = (u32)__shfl((int)pw[1][ms][w & 1], src, 64);
        wd[w] = (g >= 2) ? v1 : v0;
      }
      u32x4 pf; pf.x = wd[0]; pf.y = wd[1]; pf.z = wd[2]; pf.w = wd[3];
      pfrag[ms] = pf;
    }

    // GEMM2': Ot[c][m] += Wt-frag (i=16ct+q, k=f) * P-frag
#pragma unroll
    for (int ct = 0; ct < 16; ++ct) {
      const int off = ct * 1024 + q * 64 + ((g << 4) ^ (((q >> 1) & 3) << 4));
      u32x4 wtfrag = *(const u32x4*)(wt + off);
      mfma16(ot[ct][0], wtfrag, pfrag[0]);
      mfma16(ot[ct][1], wtfrag, pfrag[1]);
    }

    asm volatile("s_waitcnt vmcnt(0)" ::: "memory");
    __syncthreads();
  }

  // Z/T full per-row sums: reduce over 4 g-replica lanes (xor 16,32)
#pragma unroll
  for (int ms = 0; ms < 2; ++ms) {
    zz[ms] += __shfl_xor(zz[ms], 16, 64);
    zz[ms] += __shfl_xor(zz[ms], 32, 64);
    tt[ms] += __shfl_xor(tt[ms], 16, 64);
    tt[ms] += __shfl_xor(tt[ms], 32, 64);
  }

  // entropy partial: sum of (ln Z - T/Z) over wave's 32 rows (4x replicated)
  float er = 0.0f;
#pragma unroll
  for (int ms = 0; ms < 2; ++ms) er += __logf(zz[ms]) - tt[ms] / zz[ms];
#pragma unroll
  for (int d = 1; d < 64; d <<= 1) er += __shfl_xor(er, d, 64);
  if (lane == 0) entw[wave] = er * 0.25f;

  // normalize + store O (float4, coalesced: 16 rows x 64B per instr)
#pragma unroll
  for (int ms = 0; ms < 2; ++ms) {
    float rz = 1.0f / zz[ms];
    float* orow = Out + (rowbase + ms * 16 + q) * MEM_DIM;
#pragma unroll
    for (int ct = 0; ct < 16; ++ct) {
      f32x4 v = ot[ct][ms] * rz;
      *(f32x4*)(orow + ct * 16 + g * 4) = v;
    }
  }

  __syncthreads();
  if (tid == 0) entpart[blockIdx.x] = entw[0] + entw[1] + entw[2] + entw[3];
}

// batch b = 32 consecutive block partials; mean over H*W*F = 4096*1000
__global__ void ent_final(const float* __restrict__ entpart,
                          float* __restrict__ entout) {
  int b = blockIdx.x;
  int l = threadIdx.x;
  float v = (l < 32) ? entpart[b * 32 + l] : 0.0f;
#pragma unroll
  for (int d = 1; d < 64; d <<= 1) v += __shfl_xor(v, d, 64);
  if (l == 0) entout[b] = v * (1.0f / 4096000.0f);
}

extern "C" void kernel_launch(void* const* d_in, const int* in_sizes, int n_in,
                              void* d_out, int out_size, void* d_ws, size_t ws_size,
                              hipStream_t stream) {
  (void)in_sizes; (void)n_in; (void)out_size;
  const float* X = (const float*)d_in[0];   // [131072, 256] f32
  const float* W = (const float*)d_in[1];   // [1000, 256] f32
  float* Out = (float*)d_out;               // [131072,256] f32 then [32] ent
  u16* Wswz = (u16*)d_ws;                           // 512 KB
  u16* Wt = (u16*)((char*)d_ws + 524288);           // 512 KB
  float* entpart = (float*)((char*)d_ws + 1048576); // 4 KB
  if (ws_size < 1048576 + 4096) return;
  prep_kernel<<<dim3(1024), dim3(256), 0, stream>>>(W, Wswz, Wt, entpart);
  fused_kernel<<<dim3(1024), dim3(256), 0, stream>>>(X, Wswz, Wt, Out, entpart);
  ent_final<<<dim3(32), dim3(64), 0, stream>>>(entpart, Out + NOUT);
}